// Round 6
// baseline (327.067 us; speedup 1.0000x reference)
//
#include <hip/hip_runtime.h>
#include <hip/hip_bf16.h>

#define NN 8192
#define DD 128
#define DQK 256
#define EE 262144
#define EDGE_DIM 50
#define HID 32
#define CAP 96                               // per-row edge cap (Poisson(32))
#define SCALE 0.08838834764831845f          // 1/sqrt(128)
#define SCALE_LOG2E 0.12752455522410585f    // SCALE * log2(e)

using f32x4 = __attribute__((ext_vector_type(4))) float;
using f32x2 = __attribute__((ext_vector_type(2))) float;
using bf16x8 = __attribute__((ext_vector_type(8))) short;  // 8 bf16 = 4 VGPRs
using s16x4 = __attribute__((ext_vector_type(4))) short;

static __device__ __forceinline__ short f2b(float f) {
  __hip_bfloat16 h = __float2bfloat16(f);
  return __builtin_bit_cast(short, h);
}
static __device__ __forceinline__ float b2f(short s) {
  unsigned u = ((unsigned)(unsigned short)s) << 16;
  return __builtin_bit_cast(float, u);
}
// async global->LDS, 16B per lane; lds dest = wave-uniform base + lane*16
static __device__ __forceinline__ void gll(const short* g, short* l) {
  __builtin_amdgcn_global_load_lds(
      (const __attribute__((address_space(1))) void*)g,
      (__attribute__((address_space(3))) void*)l, 16, 0, 0);
}

// ---------------- K1: heterogeneous prep + MLP, one dispatch -----------------
// blocks [0,4096):    qkb[n][0:128]=mag*cos, [128:256]=mag*sin; vb16=[mag|ph]
// blocks [4096,4608): vtb[f][n] transpose via 64x64 LDS tiles
// blocks [4608,5632): edge MLP, scalar-broadcast weights.
__global__ __launch_bounds__(256) void k1_mega(
    const float* __restrict__ mag, const float* __restrict__ phase,
    short* __restrict__ qkb, short* __restrict__ vtb, short* __restrict__ vb16,
    const float* __restrict__ rbf, const float* __restrict__ W1,
    const float* __restrict__ b1, const float* __restrict__ W2,
    const float* __restrict__ b2, const int* __restrict__ eidx,
    float* __restrict__ bias, int* __restrict__ cnt, int* __restrict__ slot) {
  __shared__ float tile[64][65];
  int b = blockIdx.x;
  int tid = threadIdx.x;
  if (b < 4096) {
    int t = b * 256 + tid;
    int n = t >> 7, d = t & 127;
    float m = mag[t], p = phase[t];
    float sn, cs;
    __sincosf(p, &sn, &cs);
    qkb[(size_t)n * DQK + d] = f2b(m * cs);
    qkb[(size_t)n * DQK + 128 + d] = f2b(m * sn);
    vb16[(size_t)n * DQK + d] = f2b(m);
    vb16[(size_t)n * DQK + 128 + d] = f2b(p);
    return;
  }
  if (b < 4608) {
    int r = b - 4096;
    int bn = r & 127, bd = (r >> 7) & 1, sel = r >> 8;
    const float* src = sel ? phase : mag;
#pragma unroll
    for (int rep = 0; rep < 16; ++rep) {
      int idx = rep * 256 + tid;
      int rr = idx >> 6, c = idx & 63;
      tile[rr][c] = src[(size_t)(bn * 64 + rr) * DD + bd * 64 + c];
    }
    __syncthreads();
#pragma unroll
    for (int rep = 0; rep < 16; ++rep) {
      int idx = rep * 256 + tid;
      int rr = idx >> 6, c = idx & 63;
      vtb[(size_t)(sel * 128 + bd * 64 + rr) * NN + bn * 64 + c] = f2b(tile[c][rr]);
    }
    return;
  }
  // ---- MLP branch (1 edge/thread, scalar-broadcast weights) ----
  int e = (b - 4608) * 256 + tid;
  const float* rrow = rbf + (size_t)e * EDGE_DIM;
  f32x4 r4[12];
#pragma unroll
  for (int k = 0; k < 12; ++k) r4[k] = *reinterpret_cast<const f32x4*>(rrow + 4 * k);
  f32x2 rt2 = *reinterpret_cast<const f32x2*>(rrow + 48);
  float h[HID];
#pragma unroll
  for (int jj = 0; jj < HID; ++jj) h[jj] = b1[jj];  // uniform -> s_load
#pragma unroll
  for (int k = 0; k < 48; ++k) {
    float r = r4[k >> 2][k & 3];
#pragma unroll
    for (int jj = 0; jj < HID; ++jj) h[jj] += r * W1[k * HID + jj];  // s_load
  }
#pragma unroll
  for (int jj = 0; jj < HID; ++jj)
    h[jj] += rt2.x * W1[48 * HID + jj] + rt2.y * W1[49 * HID + jj];
  float outv = b2[0];
#pragma unroll
  for (int jj = 0; jj < HID; ++jj) {
    float x = h[jj];
    outv += W2[jj] * (x / (1.0f + __expf(-x)));
  }
  bias[e] = outv;
  int i = eidx[e];
  int p = atomicAdd(&cnt[i], 1);
  if (p < CAP) slot[i * CAP + p] = e;
}

// ---------------- K5: fused dense flash (R18: staged Q -> regs, 2 blk/CU) ----
// R17 post-mortem: direct scattered Q loads (16 lines/instr) + LDS 48K lifting
// the cap to 3 blocks/CU desynced the K-sweep -> FETCH 14->130MB, k5 147us.
// R18 keeps Q-in-registers but fixes both causes:
//   - Q staged ONCE via coalesced gll into the KV buffer (exactly 32KB), then
//     lifted LDS->reg (16 b128/lane, once), barrier, KV freed for K/V. Global
//     access pattern identical to R15's; per-chunk Q LDS reads (16/wave) gone.
//   - Ps padded +8KB so LDS=56KB > 160/3 -> hard 2 blocks/CU, same packing as
//     the 95.6us R15 kernel (2/CU uniform over the 512-block grid).
// Math bit-identical to R15 (same fragments, same MFMA order).
constexpr int TBM = 64;
constexpr int TBN = 128;

template <int NSPLIT>
__global__ __launch_bounds__(512, 4) void k5_flash(
    const short* __restrict__ qk,  // [N][256] bf16
    const short* __restrict__ vt,  // [256][N] bf16
    float* __restrict__ nump,      // [NSPLIT][N][256]
    float* __restrict__ denp) {    // [NSPLIT][N]
  constexpr int QCOLS = NN / NSPLIT;
  constexpr int NCHUNK = QCOLS / TBN;
  constexpr int GPQ = 8 / NSPLIT;
  __shared__ alignas(16) short KV[2 * TBN * 64];      // 32 KiB: Q-stage / K dbuf / V
  __shared__ alignas(16) short Ps[TBM * 128 + 4096];  // 16+8 KiB (pad -> 2 blk/CU)
  int b = blockIdx.x;
  int q = (b & 7) / GPQ;
  int rb = (b >> 3) * GPQ + (b & (GPQ - 1));
  int tid = threadIdx.x;
  int w = tid >> 6, lane = tid & 63;
  int wr = w >> 2, wc = w & 3;
  int l15 = lane & 15, quad = lane >> 4;
  int rsw = l15 & 7;  // read-side swizzle key (row&7 == l15&7 for all frags)
  int wbase = w * 64; // lane-linear staging base per wave
  int r0 = rb * TBM;
  int cbase = q * QCOLS;

  // ---- stage Q tile into KV once (coalesced gll), lift to registers ----
#pragma unroll
  for (int p = 0; p < 4; ++p) {
    int idx = p * 512 + tid;
    int row = idx >> 5, gs = idx & 31;
    gll(qk + (size_t)(r0 + row) * DQK + ((gs ^ (row & 7)) * 8),
        &KV[(p * 512 + wbase) * 8]);
  }
  __syncthreads();
  bf16x8 qreg[2][4][2];  // [rt][bk][ks], all indices static
#pragma unroll
  for (int rt = 0; rt < 2; ++rt)
#pragma unroll
    for (int bk = 0; bk < 4; ++bk)
#pragma unroll
      for (int ks = 0; ks < 2; ++ks)
        qreg[rt][bk][ks] =
            *(const bf16x8*)&KV[(wr * 32 + rt * 16 + l15) * 256 +
                                ((bk * 8 + ks * 4 + quad) ^ rsw) * 8];
  __syncthreads();  // all qreg reads done before K staging overwrites KV

  f32x4 o[2][4] = {};
  float den[2] = {0.f, 0.f};

  for (int ch = 0; ch < NCHUNK; ++ch) {
    int c0 = cbase + ch * TBN;
    // ---- stage K slice bk=0 into buf0 ----
#pragma unroll
    for (int p = 0; p < 2; ++p) {
      int idx = p * 512 + tid;
      int col = idx >> 3, gs = idx & 7;
      gll(qk + (size_t)(c0 + col) * DQK + ((gs ^ (col & 7)) * 8),
          &KV[(p * 512 + wbase) * 8]);
    }
    __syncthreads();
    f32x4 s[2][2] = {};  // s[ct][rt] = S^T fragment (swapped operands)
#pragma unroll
    for (int bk = 0; bk < 4; ++bk) {
      int buf = bk & 1;
      if (bk < 3) {
        int nb = buf ^ 1;
#pragma unroll
        for (int p = 0; p < 2; ++p) {
          int idx = p * 512 + tid;
          int col = idx >> 3, gs = idx & 7;
          gll(qk + (size_t)(c0 + col) * DQK + (bk + 1) * 64 + ((gs ^ (col & 7)) * 8),
              &KV[nb * 8192 + (p * 512 + wbase) * 8]);
        }
      }
#pragma unroll
      for (int ks = 0; ks < 2; ++ks) {
        int g = ks * 4 + quad;
        bf16x8 bb[2];
#pragma unroll
        for (int ct = 0; ct < 2; ++ct)
          bb[ct] = *(const bf16x8*)&KV[buf * 8192 + (wc * 32 + ct * 16 + l15) * 64 +
                                       (g ^ rsw) * 8];
        // swapped: A = K-frag (m = K-col), B = Q-frag (n = Q-row) -> S^T
#pragma unroll
        for (int rt = 0; rt < 2; ++rt)
#pragma unroll
          for (int ct = 0; ct < 2; ++ct)
            s[ct][rt] = __builtin_amdgcn_mfma_f32_16x16x32_bf16(
                bb[ct], qreg[rt][bk][ks], s[ct][rt], 0, 0, 0);
      }
      __syncthreads();
    }
    // ---- stage V jb=0 early (K dbuf dead); hides V latency under exp ----
#pragma unroll
    for (int p = 0; p < 4; ++p) {
      int idx = p * 512 + tid;
      int feat = idx >> 3, gs = idx & 7;
      gll(vt + (size_t)feat * NN + c0 + ((gs ^ (feat & 7)) * 8),
          &KV[(p * 512 + wbase) * 8]);
    }
    // ---- exp + packed P->LDS (S^T: lane holds 4 consecutive cols/row) ----
#pragma unroll
    for (int rt = 0; rt < 2; ++rt) {
      int row = wr * 32 + rt * 16 + l15;
#pragma unroll
      for (int ct = 0; ct < 2; ++ct) {
        s16x4 pk;
#pragma unroll
        for (int r = 0; r < 4; ++r) {
          float pv = exp2f(s[ct][rt][r] * SCALE_LOG2E);
          den[rt] += pv;
          pk[r] = f2b(pv);
        }
        int cg = wc * 4 + ct * 2 + (quad >> 1);  // col granule = col>>3
        *reinterpret_cast<s16x4*>(
            &Ps[row * 128 + ((cg ^ (row & 7)) * 8 + (quad & 1) * 4)]) = pk;
      }
    }
    __syncthreads();  // drains Ps (lgkm) + V jb=0 (vm)
    // ---- PV: V subtiles of 64 cols ----
#pragma unroll
    for (int jb = 0; jb < 2; ++jb) {
      if (jb == 1) {
        __syncthreads();  // all jb=0 vb reads done before restage
#pragma unroll
        for (int p = 0; p < 4; ++p) {
          int idx = p * 512 + tid;
          int feat = idx >> 3, gs = idx & 7;
          gll(vt + (size_t)feat * NN + c0 + 64 + ((gs ^ (feat & 7)) * 8),
              &KV[(p * 512 + wbase) * 8]);
        }
        __syncthreads();
      }
#pragma unroll
      for (int ks = 0; ks < 2; ++ks) {
        int g = ks * 4 + quad;
        bf16x8 pa[2], vb[4];
#pragma unroll
        for (int rt = 0; rt < 2; ++rt) {
          int row = wr * 32 + rt * 16 + l15;
          pa[rt] = *(const bf16x8*)&Ps[row * 128 +
                                       (((jb * 8 + g) ^ (row & 7)) * 8)];
        }
#pragma unroll
        for (int ft = 0; ft < 4; ++ft)
          vb[ft] = *(const bf16x8*)&KV[(wc * 64 + ft * 16 + l15) * 64 + (g ^ rsw) * 8];
#pragma unroll
        for (int rt = 0; rt < 2; ++rt)
#pragma unroll
          for (int ft = 0; ft < 4; ++ft)
            o[rt][ft] = __builtin_amdgcn_mfma_f32_16x16x32_bf16(pa[rt], vb[ft],
                                                                o[rt][ft], 0, 0, 0);
      }
    }
    __syncthreads();  // protect Ps/KV rewrite next chunk
  }
  // ---- epilogue: write partial num ----
  float* npB = nump + (size_t)q * NN * DQK;
#pragma unroll
  for (int rt = 0; rt < 2; ++rt)
#pragma unroll
    for (int ft = 0; ft < 4; ++ft) {
      int row = r0 + wr * 32 + rt * 16 + quad * 4;
      int feat = wc * 64 + ft * 16 + l15;
#pragma unroll
      for (int r = 0; r < 4; ++r)
        npB[(size_t)(row + r) * DQK + feat] = o[rt][ft][r];
    }
  // ---- den: S^T layout -> row = rt*16+l15; reduce across quads, then wc ----
  float* dl = reinterpret_cast<float*>(KV);  // [4][TBM], KV dead at epilogue
#pragma unroll
  for (int rt = 0; rt < 2; ++rt) {
    float d = den[rt];
    d += __shfl_xor(d, 16);
    d += __shfl_xor(d, 32);
    if (lane < 16) dl[wc * TBM + wr * 32 + rt * 16 + lane] = d;
  }
  __syncthreads();
  if (tid < TBM) {
    float d = dl[0 * TBM + tid] + dl[1 * TBM + tid] + dl[2 * TBM + tid] +
              dl[3 * TBM + tid];
    denp[q * NN + r0 + tid] = d;
  }
}

// ---------------- K6: one wave per row (R3 version, best-measured) -----------
__global__ __launch_bounds__(64) void k6_combine(
    const int* __restrict__ eidx, const float* __restrict__ bias,
    const int* __restrict__ cntArr, const int* __restrict__ slot,
    const short* __restrict__ qk, const short* __restrict__ vb16,
    const float* __restrict__ nump, const float* __restrict__ denp,
    float* __restrict__ out, int nsplit) {
  __shared__ short qs[DQK];
  __shared__ int js[CAP];
  __shared__ float bs[CAP];
  __shared__ float ess[CAP];
  __shared__ int keepf[CAP];
  __shared__ float ncl[2][32][8];
  __shared__ float dcl[2];
  int i = blockIdx.x;
  int lane = threadIdx.x;
  int cnt = cntArr[i];
  if (cnt > CAP) cnt = CAP;
  *reinterpret_cast<s16x4*>(&qs[lane * 4]) =
      *reinterpret_cast<const s16x4*>(qk + (size_t)i * DQK + lane * 4);
  for (int p = lane; p < cnt; p += 64) {
    int e = slot[i * CAP + p];
    js[p] = eidx[EE + e];
    bs[p] = bias[e];
  }
  __syncthreads();
  // ---- per-edge exp(score): 8 lanes per edge, 8 edges in flight ----
  int sub = lane & 7;
  for (int p = lane >> 3; p < cnt; p += 8) {
    int j = js[p];
    const bf16x8* kb = reinterpret_cast<const bf16x8*>(qk + (size_t)j * DQK + sub * 32);
    const bf16x8* qa = reinterpret_cast<const bf16x8*>(qs + sub * 32);
    float sp = 0.f;
#pragma unroll
    for (int t = 0; t < 4; ++t) {
      bf16x8 qv = qa[t];
      bf16x8 kv = kb[t];
#pragma unroll
      for (int u = 0; u < 8; ++u) sp += b2f(qv[u]) * b2f(kv[u]);
    }
    sp += __shfl_xor(sp, 1);
    sp += __shfl_xor(sp, 2);
    sp += __shfl_xor(sp, 4);
    if (sub == 0) ess[p] = __expf(sp * SCALE);
  }
  __syncthreads();
  // ---- exact duplicate-(i,j) merge: first occurrence keeps summed beta ----
  {
    int myp[2];
    float mybsum[2];
    int mykeep[2];
    int nm = 0;
    for (int p = lane; p < cnt; p += 64) {
      int j = js[p];
      float bsum = bs[p];
      int keep = 1;
      for (int qq = 0; qq < cnt; ++qq) {
        if (qq == p || js[qq] != j) continue;
        if (qq < p) { keep = 0; break; }
        bsum += bs[qq];
      }
      myp[nm] = p; mybsum[nm] = bsum; mykeep[nm] = keep; ++nm;
    }
    __syncthreads();
    for (int k = 0; k < nm; ++k) { bs[myp[k]] = mybsum[k]; keepf[myp[k]] = mykeep[k]; }
    __syncthreads();
  }
  // ---- correction: 2 groups of 32 lanes, one edge each; bf16x8 V-gather ----
  int grp = lane >> 5;
  int l31 = lane & 31;  // feats l31*8 .. l31*8+7
  f32x4 nc0 = {0.f, 0.f, 0.f, 0.f}, nc1 = {0.f, 0.f, 0.f, 0.f};
  float denc = 0.f;
  for (int p = grp; p < cnt; p += 2) {
    if (!keepf[p]) continue;
    float delta = ess[p] * expm1f(bs[p]);
    denc += delta;
    bf16x8 v = *reinterpret_cast<const bf16x8*>(vb16 + (size_t)js[p] * DQK + l31 * 8);
#pragma unroll
    for (int u = 0; u < 4; ++u) nc0[u] += delta * b2f(v[u]);
#pragma unroll
    for (int u = 0; u < 4; ++u) nc1[u] += delta * b2f(v[4 + u]);
  }
#pragma unroll
  for (int u = 0; u < 4; ++u) {
    ncl[grp][l31][u] = nc0[u];
    ncl[grp][l31][4 + u] = nc1[u];
  }
  if (l31 == 0) dcl[grp] = denc;
  __syncthreads();
  if (grp == 0) {
    float den = dcl[0] + dcl[1];
    f32x4 a0, a1;
#pragma unroll
    for (int u = 0; u < 4; ++u) {
      a0[u] = ncl[0][l31][u] + ncl[1][l31][u];
      a1[u] = ncl[0][l31][4 + u] + ncl[1][l31][4 + u];
    }
    for (int qq = 0; qq < nsplit; ++qq) {
      const float* np = nump + ((size_t)qq * NN + i) * DQK + l31 * 8;
      a0 += *reinterpret_cast<const f32x4*>(np);
      a1 += *reinterpret_cast<const f32x4*>(np + 4);
      den += denp[qq * NN + i];
    }
    float inv = 1.0f / den;
    a0 *= inv;
    a1 *= inv;
    // feats f = l31*8..+7; f<128 -> new_mag, else new_phase (no 128-crossing)
    float* dst = (l31 < 16) ? (out + (size_t)i * DD + l31 * 8)
                            : (out + (size_t)NN * DD + (size_t)i * DD + l31 * 8 - 128);
    *reinterpret_cast<f32x4*>(dst) = a0;
    *reinterpret_cast<f32x4*>(dst + 4) = a1;
  }
}

// ---------------- workspace layout -------------------------------------------
constexpr size_t OFF_QK = 0;                                   // 4 MiB bf16
constexpr size_t OFF_VT = (size_t)NN * DQK * 2;                // 4 MiB bf16
constexpr size_t OFF_VB16 = OFF_VT + (size_t)DQK * NN * 2;     // 4 MiB bf16
constexpr size_t OFF_BIAS = OFF_VB16 + (size_t)NN * DQK * 2;   // 1 MiB f32
constexpr size_t OFF_CNT = OFF_BIAS + (size_t)EE * 4;
constexpr size_t OFF_SLOT = OFF_CNT + (size_t)NN * 4;
constexpr size_t OFF_NUMP = (OFF_SLOT + (size_t)NN * CAP * 4 + 255) & ~(size_t)255;
constexpr size_t WS_NEED4 = OFF_NUMP + 4ull * NN * DQK * 4 + 4ull * NN * 4;
constexpr size_t WS_NEED2 = OFF_NUMP + 2ull * NN * DQK * 4 + 2ull * NN * 4;

extern "C" void kernel_launch(void* const* d_in, const int* in_sizes, int n_in,
                              void* d_out, int out_size, void* d_ws, size_t ws_size,
                              hipStream_t stream) {
  const float* mag = (const float*)d_in[0];
  const float* phase = (const float*)d_in[1];
  const int* eidx = (const int*)d_in[2];
  const float* rbf = (const float*)d_in[3];
  const float* W1 = (const float*)d_in[4];
  const float* b1 = (const float*)d_in[5];
  const float* W2 = (const float*)d_in[6];
  const float* b2 = (const float*)d_in[7];
  float* out = (float*)d_out;
  char* ws = (char*)d_ws;
  if (ws_size < WS_NEED2) return;
  int nsplit = (ws_size >= WS_NEED4) ? 4 : 2;

  short* qkb = (short*)(ws + OFF_QK);
  short* vtb = (short*)(ws + OFF_VT);
  short* vb16 = (short*)(ws + OFF_VB16);
  float* bias = (float*)(ws + OFF_BIAS);
  int* cnt = (int*)(ws + OFF_CNT);
  int* slot = (int*)(ws + OFF_SLOT);
  float* nump = (float*)(ws + OFF_NUMP);
  float* denp = (float*)(ws + OFF_NUMP + (size_t)nsplit * NN * DQK * 4);

  hipMemsetAsync(cnt, 0, (size_t)NN * 4, stream);
  k1_mega<<<5632, 256, 0, stream>>>(mag, phase, qkb, vtb, vb16, rbf, W1, b1, W2,
                                    b2, eidx, bias, cnt, slot);
  if (nsplit == 4)
    k5_flash<4><<<(NN / TBM) * 4, 512, 0, stream>>>(qkb, vtb, nump, denp);
  else
    k5_flash<2><<<(NN / TBM) * 2, 512, 0, stream>>>(qkb, vtb, nump, denp);
  k6_combine<<<NN, 64, 0, stream>>>(eidx, bias, cnt, slot, qkb, vb16, nump, denp,
                                    out, nsplit);
}

// Round 7
// 305.120 us; speedup vs baseline: 1.0719x; 1.0719x over previous
//
#include <hip/hip_runtime.h>
#include <hip/hip_bf16.h>

#define NN 8192
#define DD 128
#define DQK 256
#define EE 262144
#define EDGE_DIM 50
#define HID 32
#define CAP 96                               // per-row edge cap (Poisson(32))
#define SCALE 0.08838834764831845f          // 1/sqrt(128)
#define SCALE_LOG2E 0.12752455522410585f    // SCALE * log2(e)

using f32x4 = __attribute__((ext_vector_type(4))) float;
using f32x2 = __attribute__((ext_vector_type(2))) float;
using bf16x8 = __attribute__((ext_vector_type(8))) short;  // 8 bf16 = 4 VGPRs
using s16x4 = __attribute__((ext_vector_type(4))) short;

static __device__ __forceinline__ short f2b(float f) {
  __hip_bfloat16 h = __float2bfloat16(f);
  return __builtin_bit_cast(short, h);
}
static __device__ __forceinline__ float b2f(short s) {
  unsigned u = ((unsigned)(unsigned short)s) << 16;
  return __builtin_bit_cast(float, u);
}
// async global->LDS, 16B per lane; lds dest = wave-uniform base + lane*16
static __device__ __forceinline__ void gll(const short* g, short* l) {
  __builtin_amdgcn_global_load_lds(
      (const __attribute__((address_space(1))) void*)g,
      (__attribute__((address_space(3))) void*)l, 16, 0, 0);
}

// ---------------- K1: heterogeneous prep + MLP, one dispatch -----------------
// blocks [0,4096):    qkb[n][0:128]=mag*cos, [128:256]=mag*sin; vb16=[mag|ph]
// blocks [4096,4608): vtb[f][n] transpose via 64x64 LDS tiles
// blocks [4608,5632): edge MLP, scalar-broadcast weights.
__global__ __launch_bounds__(256) void k1_mega(
    const float* __restrict__ mag, const float* __restrict__ phase,
    short* __restrict__ qkb, short* __restrict__ vtb, short* __restrict__ vb16,
    const float* __restrict__ rbf, const float* __restrict__ W1,
    const float* __restrict__ b1, const float* __restrict__ W2,
    const float* __restrict__ b2, const int* __restrict__ eidx,
    float* __restrict__ bias, int* __restrict__ cnt, int* __restrict__ slot) {
  __shared__ float tile[64][65];
  int b = blockIdx.x;
  int tid = threadIdx.x;
  if (b < 4096) {
    int t = b * 256 + tid;
    int n = t >> 7, d = t & 127;
    float m = mag[t], p = phase[t];
    float sn, cs;
    __sincosf(p, &sn, &cs);
    qkb[(size_t)n * DQK + d] = f2b(m * cs);
    qkb[(size_t)n * DQK + 128 + d] = f2b(m * sn);
    vb16[(size_t)n * DQK + d] = f2b(m);
    vb16[(size_t)n * DQK + 128 + d] = f2b(p);
    return;
  }
  if (b < 4608) {
    int r = b - 4096;
    int bn = r & 127, bd = (r >> 7) & 1, sel = r >> 8;
    const float* src = sel ? phase : mag;
#pragma unroll
    for (int rep = 0; rep < 16; ++rep) {
      int idx = rep * 256 + tid;
      int rr = idx >> 6, c = idx & 63;
      tile[rr][c] = src[(size_t)(bn * 64 + rr) * DD + bd * 64 + c];
    }
    __syncthreads();
#pragma unroll
    for (int rep = 0; rep < 16; ++rep) {
      int idx = rep * 256 + tid;
      int rr = idx >> 6, c = idx & 63;
      vtb[(size_t)(sel * 128 + bd * 64 + rr) * NN + bn * 64 + c] = f2b(tile[c][rr]);
    }
    return;
  }
  // ---- MLP branch (1 edge/thread, scalar-broadcast weights) ----
  int e = (b - 4608) * 256 + tid;
  const float* rrow = rbf + (size_t)e * EDGE_DIM;
  f32x4 r4[12];
#pragma unroll
  for (int k = 0; k < 12; ++k) r4[k] = *reinterpret_cast<const f32x4*>(rrow + 4 * k);
  f32x2 rt2 = *reinterpret_cast<const f32x2*>(rrow + 48);
  float h[HID];
#pragma unroll
  for (int jj = 0; jj < HID; ++jj) h[jj] = b1[jj];  // uniform -> s_load
#pragma unroll
  for (int k = 0; k < 48; ++k) {
    float r = r4[k >> 2][k & 3];
#pragma unroll
    for (int jj = 0; jj < HID; ++jj) h[jj] += r * W1[k * HID + jj];  // s_load
  }
#pragma unroll
  for (int jj = 0; jj < HID; ++jj)
    h[jj] += rt2.x * W1[48 * HID + jj] + rt2.y * W1[49 * HID + jj];
  float outv = b2[0];
#pragma unroll
  for (int jj = 0; jj < HID; ++jj) {
    float x = h[jj];
    outv += W2[jj] * (x / (1.0f + __expf(-x)));
  }
  bias[e] = outv;
  int i = eidx[e];
  int p = atomicAdd(&cnt[i], 1);
  if (p < CAP) slot[i * CAP + p] = e;
}

// ---------------- K5: fused dense flash (EXACT R15, 95.6us proven) -----------
// R19: k5 code reverted to R15 byte-for-byte (S^T + packed Ps writes). The
// only change: b0 grid offset so the grid can be launched as TWO half
// dispatches -> k1_mega and k6_combine surface in the top-5 profile table
// (attribution for the ~166us non-k5 time, unmeasured for 6 rounds).
// Register budget lesson (R17/R18): launch_bounds(512,4) = 128 unified
// VGPR+AGPR; acc (~48) + base (~60) leaves NO room for Q-in-regs -> spills
// to scratch (FETCH 14->226MB). Do not add per-lane state to k5.
constexpr int TBM = 64;
constexpr int TBN = 128;

template <int NSPLIT>
__global__ __launch_bounds__(512, 4) void k5_flash(
    const short* __restrict__ qk,  // [N][256] bf16
    const short* __restrict__ vt,  // [256][N] bf16
    float* __restrict__ nump,      // [NSPLIT][N][256]
    float* __restrict__ denp,      // [NSPLIT][N]
    int b0) {                      // grid offset (visibility split)
  constexpr int QCOLS = NN / NSPLIT;
  constexpr int NCHUNK = QCOLS / TBN;
  constexpr int GPQ = 8 / NSPLIT;
  __shared__ alignas(16) short Qs[TBM * 256];     // 32 KiB, swizzled
  __shared__ alignas(16) short KV[2 * TBN * 64];  // 32 KiB: K dbuf / V subtile
  __shared__ alignas(16) short Ps[TBM * 128];     // 16 KiB, swizzled
  int b = blockIdx.x + b0;
  int q = (b & 7) / GPQ;
  int rb = (b >> 3) * GPQ + (b & (GPQ - 1));
  int tid = threadIdx.x;
  int w = tid >> 6, lane = tid & 63;
  int wr = w >> 2, wc = w & 3;
  int l15 = lane & 15, quad = lane >> 4;
  int rsw = l15 & 7;  // read-side swizzle key (row&7 == l15&7 for all frags)
  int wbase = w * 64; // lane-linear staging base per wave
  int r0 = rb * TBM;
  int cbase = q * QCOLS;

  // ---- stage Q tile once: 4 passes x 8KB, direct to LDS ----
#pragma unroll
  for (int p = 0; p < 4; ++p) {
    int idx = p * 512 + tid;
    int row = idx >> 5, gs = idx & 31;
    gll(qk + (size_t)(r0 + row) * DQK + ((gs ^ (row & 7)) * 8),
        &Qs[(p * 512 + wbase) * 8]);
  }

  f32x4 o[2][4] = {};
  float den[2] = {0.f, 0.f};
  __syncthreads();

  for (int ch = 0; ch < NCHUNK; ++ch) {
    int c0 = cbase + ch * TBN;
    // ---- stage K slice bk=0 into buf0 ----
#pragma unroll
    for (int p = 0; p < 2; ++p) {
      int idx = p * 512 + tid;
      int col = idx >> 3, gs = idx & 7;
      gll(qk + (size_t)(c0 + col) * DQK + ((gs ^ (col & 7)) * 8),
          &KV[(p * 512 + wbase) * 8]);
    }
    __syncthreads();
    f32x4 s[2][2] = {};  // s[ct][rt] = S^T fragment (swapped operands)
#pragma unroll
    for (int bk = 0; bk < 4; ++bk) {
      int buf = bk & 1;
      if (bk < 3) {
        int nb = buf ^ 1;
#pragma unroll
        for (int p = 0; p < 2; ++p) {
          int idx = p * 512 + tid;
          int col = idx >> 3, gs = idx & 7;
          gll(qk + (size_t)(c0 + col) * DQK + (bk + 1) * 64 + ((gs ^ (col & 7)) * 8),
              &KV[nb * 8192 + (p * 512 + wbase) * 8]);
        }
      }
#pragma unroll
      for (int ks = 0; ks < 2; ++ks) {
        int g = ks * 4 + quad;
        bf16x8 a[2], bb[2];
#pragma unroll
        for (int rt = 0; rt < 2; ++rt)
          a[rt] = *(const bf16x8*)&Qs[(wr * 32 + rt * 16 + l15) * 256 +
                                      ((bk * 8 + g) ^ rsw) * 8];
#pragma unroll
        for (int ct = 0; ct < 2; ++ct)
          bb[ct] = *(const bf16x8*)&KV[buf * 8192 + (wc * 32 + ct * 16 + l15) * 64 +
                                       (g ^ rsw) * 8];
        // swapped: A = K-frag (m = K-col), B = Q-frag (n = Q-row) -> S^T
#pragma unroll
        for (int rt = 0; rt < 2; ++rt)
#pragma unroll
          for (int ct = 0; ct < 2; ++ct)
            s[ct][rt] = __builtin_amdgcn_mfma_f32_16x16x32_bf16(bb[ct], a[rt],
                                                                s[ct][rt], 0, 0, 0);
      }
      __syncthreads();
    }
    // ---- stage V jb=0 early (K dbuf dead); hides V latency under exp ----
#pragma unroll
    for (int p = 0; p < 4; ++p) {
      int idx = p * 512 + tid;
      int feat = idx >> 3, gs = idx & 7;
      gll(vt + (size_t)feat * NN + c0 + ((gs ^ (feat & 7)) * 8),
          &KV[(p * 512 + wbase) * 8]);
    }
    // ---- exp + packed P->LDS (S^T: lane holds 4 consecutive cols/row) ----
#pragma unroll
    for (int rt = 0; rt < 2; ++rt) {
      int row = wr * 32 + rt * 16 + l15;
#pragma unroll
      for (int ct = 0; ct < 2; ++ct) {
        s16x4 pk;
#pragma unroll
        for (int r = 0; r < 4; ++r) {
          float pv = exp2f(s[ct][rt][r] * SCALE_LOG2E);
          den[rt] += pv;
          pk[r] = f2b(pv);
        }
        int cg = wc * 4 + ct * 2 + (quad >> 1);  // col granule = col>>3
        *reinterpret_cast<s16x4*>(
            &Ps[row * 128 + ((cg ^ (row & 7)) * 8 + (quad & 1) * 4)]) = pk;
      }
    }
    __syncthreads();  // drains Ps (lgkm) + V jb=0 (vm)
    // ---- PV: V subtiles of 64 cols ----
#pragma unroll
    for (int jb = 0; jb < 2; ++jb) {
      if (jb == 1) {
        __syncthreads();  // all jb=0 vb reads done before restage
#pragma unroll
        for (int p = 0; p < 4; ++p) {
          int idx = p * 512 + tid;
          int feat = idx >> 3, gs = idx & 7;
          gll(vt + (size_t)feat * NN + c0 + 64 + ((gs ^ (feat & 7)) * 8),
              &KV[(p * 512 + wbase) * 8]);
        }
        __syncthreads();
      }
#pragma unroll
      for (int ks = 0; ks < 2; ++ks) {
        int g = ks * 4 + quad;
        bf16x8 pa[2], vb[4];
#pragma unroll
        for (int rt = 0; rt < 2; ++rt) {
          int row = wr * 32 + rt * 16 + l15;
          pa[rt] = *(const bf16x8*)&Ps[row * 128 +
                                       (((jb * 8 + g) ^ (row & 7)) * 8)];
        }
#pragma unroll
        for (int ft = 0; ft < 4; ++ft)
          vb[ft] = *(const bf16x8*)&KV[(wc * 64 + ft * 16 + l15) * 64 + (g ^ rsw) * 8];
#pragma unroll
        for (int rt = 0; rt < 2; ++rt)
#pragma unroll
          for (int ft = 0; ft < 4; ++ft)
            o[rt][ft] = __builtin_amdgcn_mfma_f32_16x16x32_bf16(pa[rt], vb[ft],
                                                                o[rt][ft], 0, 0, 0);
      }
    }
    __syncthreads();  // protect Ps/KV rewrite next chunk
  }
  // ---- epilogue: write partial num ----
  float* npB = nump + (size_t)q * NN * DQK;
#pragma unroll
  for (int rt = 0; rt < 2; ++rt)
#pragma unroll
    for (int ft = 0; ft < 4; ++ft) {
      int row = r0 + wr * 32 + rt * 16 + quad * 4;
      int feat = wc * 64 + ft * 16 + l15;
#pragma unroll
      for (int r = 0; r < 4; ++r)
        npB[(size_t)(row + r) * DQK + feat] = o[rt][ft][r];
    }
  // ---- den: S^T layout -> row = rt*16+l15; reduce across quads, then wc ----
  float* dl = reinterpret_cast<float*>(KV);  // [4][TBM], KV dead at epilogue
#pragma unroll
  for (int rt = 0; rt < 2; ++rt) {
    float d = den[rt];
    d += __shfl_xor(d, 16);
    d += __shfl_xor(d, 32);
    if (lane < 16) dl[wc * TBM + wr * 32 + rt * 16 + lane] = d;
  }
  __syncthreads();
  if (tid < TBM) {
    float d = dl[0 * TBM + tid] + dl[1 * TBM + tid] + dl[2 * TBM + tid] +
              dl[3 * TBM + tid];
    denp[q * NN + r0 + tid] = d;
  }
}

// ---------------- K6: one wave per row (R3 version, best-measured) -----------
__global__ __launch_bounds__(64) void k6_combine(
    const int* __restrict__ eidx, const float* __restrict__ bias,
    const int* __restrict__ cntArr, const int* __restrict__ slot,
    const short* __restrict__ qk, const short* __restrict__ vb16,
    const float* __restrict__ nump, const float* __restrict__ denp,
    float* __restrict__ out, int nsplit) {
  __shared__ short qs[DQK];
  __shared__ int js[CAP];
  __shared__ float bs[CAP];
  __shared__ float ess[CAP];
  __shared__ int keepf[CAP];
  __shared__ float ncl[2][32][8];
  __shared__ float dcl[2];
  int i = blockIdx.x;
  int lane = threadIdx.x;
  int cnt = cntArr[i];
  if (cnt > CAP) cnt = CAP;
  *reinterpret_cast<s16x4*>(&qs[lane * 4]) =
      *reinterpret_cast<const s16x4*>(qk + (size_t)i * DQK + lane * 4);
  for (int p = lane; p < cnt; p += 64) {
    int e = slot[i * CAP + p];
    js[p] = eidx[EE + e];
    bs[p] = bias[e];
  }
  __syncthreads();
  // ---- per-edge exp(score): 8 lanes per edge, 8 edges in flight ----
  int sub = lane & 7;
  for (int p = lane >> 3; p < cnt; p += 8) {
    int j = js[p];
    const bf16x8* kb = reinterpret_cast<const bf16x8*>(qk + (size_t)j * DQK + sub * 32);
    const bf16x8* qa = reinterpret_cast<const bf16x8*>(qs + sub * 32);
    float sp = 0.f;
#pragma unroll
    for (int t = 0; t < 4; ++t) {
      bf16x8 qv = qa[t];
      bf16x8 kv = kb[t];
#pragma unroll
      for (int u = 0; u < 8; ++u) sp += b2f(qv[u]) * b2f(kv[u]);
    }
    sp += __shfl_xor(sp, 1);
    sp += __shfl_xor(sp, 2);
    sp += __shfl_xor(sp, 4);
    if (sub == 0) ess[p] = __expf(sp * SCALE);
  }
  __syncthreads();
  // ---- exact duplicate-(i,j) merge: first occurrence keeps summed beta ----
  {
    int myp[2];
    float mybsum[2];
    int mykeep[2];
    int nm = 0;
    for (int p = lane; p < cnt; p += 64) {
      int j = js[p];
      float bsum = bs[p];
      int keep = 1;
      for (int qq = 0; qq < cnt; ++qq) {
        if (qq == p || js[qq] != j) continue;
        if (qq < p) { keep = 0; break; }
        bsum += bs[qq];
      }
      myp[nm] = p; mybsum[nm] = bsum; mykeep[nm] = keep; ++nm;
    }
    __syncthreads();
    for (int k = 0; k < nm; ++k) { bs[myp[k]] = mybsum[k]; keepf[myp[k]] = mykeep[k]; }
    __syncthreads();
  }
  // ---- correction: 2 groups of 32 lanes, one edge each; bf16x8 V-gather ----
  int grp = lane >> 5;
  int l31 = lane & 31;  // feats l31*8 .. l31*8+7
  f32x4 nc0 = {0.f, 0.f, 0.f, 0.f}, nc1 = {0.f, 0.f, 0.f, 0.f};
  float denc = 0.f;
  for (int p = grp; p < cnt; p += 2) {
    if (!keepf[p]) continue;
    float delta = ess[p] * expm1f(bs[p]);
    denc += delta;
    bf16x8 v = *reinterpret_cast<const bf16x8*>(vb16 + (size_t)js[p] * DQK + l31 * 8);
#pragma unroll
    for (int u = 0; u < 4; ++u) nc0[u] += delta * b2f(v[u]);
#pragma unroll
    for (int u = 0; u < 4; ++u) nc1[u] += delta * b2f(v[4 + u]);
  }
#pragma unroll
  for (int u = 0; u < 4; ++u) {
    ncl[grp][l31][u] = nc0[u];
    ncl[grp][l31][4 + u] = nc1[u];
  }
  if (l31 == 0) dcl[grp] = denc;
  __syncthreads();
  if (grp == 0) {
    float den = dcl[0] + dcl[1];
    f32x4 a0, a1;
#pragma unroll
    for (int u = 0; u < 4; ++u) {
      a0[u] = ncl[0][l31][u] + ncl[1][l31][u];
      a1[u] = ncl[0][l31][4 + u] + ncl[1][l31][4 + u];
    }
    for (int qq = 0; qq < nsplit; ++qq) {
      const float* np = nump + ((size_t)qq * NN + i) * DQK + l31 * 8;
      a0 += *reinterpret_cast<const f32x4*>(np);
      a1 += *reinterpret_cast<const f32x4*>(np + 4);
      den += denp[qq * NN + i];
    }
    float inv = 1.0f / den;
    a0 *= inv;
    a1 *= inv;
    // feats f = l31*8..+7; f<128 -> new_mag, else new_phase (no 128-crossing)
    float* dst = (l31 < 16) ? (out + (size_t)i * DD + l31 * 8)
                            : (out + (size_t)NN * DD + (size_t)i * DD + l31 * 8 - 128);
    *reinterpret_cast<f32x4*>(dst) = a0;
    *reinterpret_cast<f32x4*>(dst + 4) = a1;
  }
}

// ---------------- workspace layout -------------------------------------------
constexpr size_t OFF_QK = 0;                                   // 4 MiB bf16
constexpr size_t OFF_VT = (size_t)NN * DQK * 2;                // 4 MiB bf16
constexpr size_t OFF_VB16 = OFF_VT + (size_t)DQK * NN * 2;     // 4 MiB bf16
constexpr size_t OFF_BIAS = OFF_VB16 + (size_t)NN * DQK * 2;   // 1 MiB f32
constexpr size_t OFF_CNT = OFF_BIAS + (size_t)EE * 4;
constexpr size_t OFF_SLOT = OFF_CNT + (size_t)NN * 4;
constexpr size_t OFF_NUMP = (OFF_SLOT + (size_t)NN * CAP * 4 + 255) & ~(size_t)255;
constexpr size_t WS_NEED4 = OFF_NUMP + 4ull * NN * DQK * 4 + 4ull * NN * 4;
constexpr size_t WS_NEED2 = OFF_NUMP + 2ull * NN * DQK * 4 + 2ull * NN * 4;

extern "C" void kernel_launch(void* const* d_in, const int* in_sizes, int n_in,
                              void* d_out, int out_size, void* d_ws, size_t ws_size,
                              hipStream_t stream) {
  const float* mag = (const float*)d_in[0];
  const float* phase = (const float*)d_in[1];
  const int* eidx = (const int*)d_in[2];
  const float* rbf = (const float*)d_in[3];
  const float* W1 = (const float*)d_in[4];
  const float* b1 = (const float*)d_in[5];
  const float* W2 = (const float*)d_in[6];
  const float* b2 = (const float*)d_in[7];
  float* out = (float*)d_out;
  char* ws = (char*)d_ws;
  if (ws_size < WS_NEED2) return;
  int nsplit = (ws_size >= WS_NEED4) ? 4 : 2;

  short* qkb = (short*)(ws + OFF_QK);
  short* vtb = (short*)(ws + OFF_VT);
  short* vb16 = (short*)(ws + OFF_VB16);
  float* bias = (float*)(ws + OFF_BIAS);
  int* cnt = (int*)(ws + OFF_CNT);
  int* slot = (int*)(ws + OFF_SLOT);
  float* nump = (float*)(ws + OFF_NUMP);
  float* denp = (float*)(ws + OFF_NUMP + (size_t)nsplit * NN * DQK * 4);

  hipMemsetAsync(cnt, 0, (size_t)NN * 4, stream);
  k1_mega<<<5632, 256, 0, stream>>>(mag, phase, qkb, vtb, vb16, rbf, W1, b1, W2,
                                    b2, eidx, bias, cnt, slot);
  if (nsplit == 4) {
    int half = (NN / TBM) * 4 / 2;  // 256
    k5_flash<4><<<half, 512, 0, stream>>>(qkb, vtb, nump, denp, 0);
    k5_flash<4><<<half, 512, 0, stream>>>(qkb, vtb, nump, denp, half);
  } else {
    int half = (NN / TBM) * 2 / 2;  // 128
    k5_flash<2><<<half, 512, 0, stream>>>(qkb, vtb, nump, denp, 0);
    k5_flash<2><<<half, 512, 0, stream>>>(qkb, vtb, nump, denp, half);
  }
  k6_combine<<<NN, 64, 0, stream>>>(eidx, bias, cnt, slot, qkb, vb16, nump, denp,
                                    out, nsplit);
}

// Round 8
// 261.901 us; speedup vs baseline: 1.2488x; 1.1650x over previous
//
#include <hip/hip_runtime.h>
#include <hip/hip_bf16.h>

#define NN 8192
#define DD 128
#define DQK 256
#define EE 262144
#define EDGE_DIM 50
#define HID 32
#define CAP 96                               // per-row edge cap (Poisson(32))
#define SCALE 0.08838834764831845f          // 1/sqrt(128)
#define SCALE_LOG2E 0.12752455522410585f    // SCALE * log2(e)

using f32x4 = __attribute__((ext_vector_type(4))) float;
using f32x2 = __attribute__((ext_vector_type(2))) float;
using bf16x8 = __attribute__((ext_vector_type(8))) short;  // 8 bf16 = 4 VGPRs
using s16x4 = __attribute__((ext_vector_type(4))) short;

static __device__ __forceinline__ short f2b(float f) {
  __hip_bfloat16 h = __float2bfloat16(f);
  return __builtin_bit_cast(short, h);
}
static __device__ __forceinline__ float b2f(short s) {
  unsigned u = ((unsigned)(unsigned short)s) << 16;
  return __builtin_bit_cast(float, u);
}
// async global->LDS, 16B per lane; lds dest = wave-uniform base + lane*16
static __device__ __forceinline__ void gll(const short* g, short* l) {
  __builtin_amdgcn_global_load_lds(
      (const __attribute__((address_space(1))) void*)g,
      (__attribute__((address_space(3))) void*)l, 16, 0, 0);
}

// ---------------- K1: heterogeneous prep + MLP, one dispatch (R3, frozen) ----
// blocks [0,4096):    qkb[n][0:128]=mag*cos, [128:256]=mag*sin; vb16=[mag|ph]
// blocks [4096,4608): vtb[f][n] transpose via 64x64 LDS tiles
// blocks [4608,5632): edge MLP, scalar-broadcast weights.
__global__ __launch_bounds__(256) void k1_mega(
    const float* __restrict__ mag, const float* __restrict__ phase,
    short* __restrict__ qkb, short* __restrict__ vtb, short* __restrict__ vb16,
    const float* __restrict__ rbf, const float* __restrict__ W1,
    const float* __restrict__ b1, const float* __restrict__ W2,
    const float* __restrict__ b2, const int* __restrict__ eidx,
    float* __restrict__ bias, int* __restrict__ cnt, int* __restrict__ slot) {
  __shared__ float tile[64][65];
  int b = blockIdx.x;
  int tid = threadIdx.x;
  if (b < 4096) {
    int t = b * 256 + tid;
    int n = t >> 7, d = t & 127;
    float m = mag[t], p = phase[t];
    float sn, cs;
    __sincosf(p, &sn, &cs);
    qkb[(size_t)n * DQK + d] = f2b(m * cs);
    qkb[(size_t)n * DQK + 128 + d] = f2b(m * sn);
    vb16[(size_t)n * DQK + d] = f2b(m);
    vb16[(size_t)n * DQK + 128 + d] = f2b(p);
    return;
  }
  if (b < 4608) {
    int r = b - 4096;
    int bn = r & 127, bd = (r >> 7) & 1, sel = r >> 8;
    const float* src = sel ? phase : mag;
#pragma unroll
    for (int rep = 0; rep < 16; ++rep) {
      int idx = rep * 256 + tid;
      int rr = idx >> 6, c = idx & 63;
      tile[rr][c] = src[(size_t)(bn * 64 + rr) * DD + bd * 64 + c];
    }
    __syncthreads();
#pragma unroll
    for (int rep = 0; rep < 16; ++rep) {
      int idx = rep * 256 + tid;
      int rr = idx >> 6, c = idx & 63;
      vtb[(size_t)(sel * 128 + bd * 64 + rr) * NN + bn * 64 + c] = f2b(tile[c][rr]);
    }
    return;
  }
  // ---- MLP branch (1 edge/thread, scalar-broadcast weights) ----
  int e = (b - 4608) * 256 + tid;
  const float* rrow = rbf + (size_t)e * EDGE_DIM;
  f32x4 r4[12];
#pragma unroll
  for (int k = 0; k < 12; ++k) r4[k] = *reinterpret_cast<const f32x4*>(rrow + 4 * k);
  f32x2 rt2 = *reinterpret_cast<const f32x2*>(rrow + 48);
  float h[HID];
#pragma unroll
  for (int jj = 0; jj < HID; ++jj) h[jj] = b1[jj];  // uniform -> s_load
#pragma unroll
  for (int k = 0; k < 48; ++k) {
    float r = r4[k >> 2][k & 3];
#pragma unroll
    for (int jj = 0; jj < HID; ++jj) h[jj] += r * W1[k * HID + jj];  // s_load
  }
#pragma unroll
  for (int jj = 0; jj < HID; ++jj)
    h[jj] += rt2.x * W1[48 * HID + jj] + rt2.y * W1[49 * HID + jj];
  float outv = b2[0];
#pragma unroll
  for (int jj = 0; jj < HID; ++jj) {
    float x = h[jj];
    outv += W2[jj] * (x / (1.0f + __expf(-x)));
  }
  bias[e] = outv;
  int i = eidx[e];
  int p = atomicAdd(&cnt[i], 1);
  if (p < CAP) slot[i * CAP + p] = e;
}

// ---------------- K5: fused dense flash (EXACT R15, 95.6us, FROZEN) ----------
// Structural probes exhausted: R13 counted-vmcnt flat; R14 direct-to-reg K/V
// 2.4x worse; R17/R18 Q-in-regs spills (128 unified VGPR+AGPR budget full);
// R19 half-grid = 1 blk/CU = 1.6x less throughput (latency-bound, needs the
// 2 blk/CU overlap; 3 blk/CU impossible at 80K LDS). 95.6us is this
// structure's floor. Do not touch.
constexpr int TBM = 64;
constexpr int TBN = 128;

template <int NSPLIT>
__global__ __launch_bounds__(512, 4) void k5_flash(
    const short* __restrict__ qk,  // [N][256] bf16
    const short* __restrict__ vt,  // [256][N] bf16
    float* __restrict__ nump,      // [NSPLIT][N][256]
    float* __restrict__ denp) {    // [NSPLIT][N]
  constexpr int QCOLS = NN / NSPLIT;
  constexpr int NCHUNK = QCOLS / TBN;
  constexpr int GPQ = 8 / NSPLIT;
  __shared__ alignas(16) short Qs[TBM * 256];     // 32 KiB, swizzled
  __shared__ alignas(16) short KV[2 * TBN * 64];  // 32 KiB: K dbuf / V subtile
  __shared__ alignas(16) short Ps[TBM * 128];     // 16 KiB, swizzled
  int b = blockIdx.x;
  int q = (b & 7) / GPQ;
  int rb = (b >> 3) * GPQ + (b & (GPQ - 1));
  int tid = threadIdx.x;
  int w = tid >> 6, lane = tid & 63;
  int wr = w >> 2, wc = w & 3;
  int l15 = lane & 15, quad = lane >> 4;
  int rsw = l15 & 7;  // read-side swizzle key (row&7 == l15&7 for all frags)
  int wbase = w * 64; // lane-linear staging base per wave
  int r0 = rb * TBM;
  int cbase = q * QCOLS;

  // ---- stage Q tile once: 4 passes x 8KB, direct to LDS ----
#pragma unroll
  for (int p = 0; p < 4; ++p) {
    int idx = p * 512 + tid;
    int row = idx >> 5, gs = idx & 31;
    gll(qk + (size_t)(r0 + row) * DQK + ((gs ^ (row & 7)) * 8),
        &Qs[(p * 512 + wbase) * 8]);
  }

  f32x4 o[2][4] = {};
  float den[2] = {0.f, 0.f};
  __syncthreads();

  for (int ch = 0; ch < NCHUNK; ++ch) {
    int c0 = cbase + ch * TBN;
    // ---- stage K slice bk=0 into buf0 ----
#pragma unroll
    for (int p = 0; p < 2; ++p) {
      int idx = p * 512 + tid;
      int col = idx >> 3, gs = idx & 7;
      gll(qk + (size_t)(c0 + col) * DQK + ((gs ^ (col & 7)) * 8),
          &KV[(p * 512 + wbase) * 8]);
    }
    __syncthreads();
    f32x4 s[2][2] = {};  // s[ct][rt] = S^T fragment (swapped operands)
#pragma unroll
    for (int bk = 0; bk < 4; ++bk) {
      int buf = bk & 1;
      if (bk < 3) {
        int nb = buf ^ 1;
#pragma unroll
        for (int p = 0; p < 2; ++p) {
          int idx = p * 512 + tid;
          int col = idx >> 3, gs = idx & 7;
          gll(qk + (size_t)(c0 + col) * DQK + (bk + 1) * 64 + ((gs ^ (col & 7)) * 8),
              &KV[nb * 8192 + (p * 512 + wbase) * 8]);
        }
      }
#pragma unroll
      for (int ks = 0; ks < 2; ++ks) {
        int g = ks * 4 + quad;
        bf16x8 a[2], bb[2];
#pragma unroll
        for (int rt = 0; rt < 2; ++rt)
          a[rt] = *(const bf16x8*)&Qs[(wr * 32 + rt * 16 + l15) * 256 +
                                      ((bk * 8 + g) ^ rsw) * 8];
#pragma unroll
        for (int ct = 0; ct < 2; ++ct)
          bb[ct] = *(const bf16x8*)&KV[buf * 8192 + (wc * 32 + ct * 16 + l15) * 64 +
                                       (g ^ rsw) * 8];
        // swapped: A = K-frag (m = K-col), B = Q-frag (n = Q-row) -> S^T
#pragma unroll
        for (int rt = 0; rt < 2; ++rt)
#pragma unroll
          for (int ct = 0; ct < 2; ++ct)
            s[ct][rt] = __builtin_amdgcn_mfma_f32_16x16x32_bf16(bb[ct], a[rt],
                                                                s[ct][rt], 0, 0, 0);
      }
      __syncthreads();
    }
    // ---- stage V jb=0 early (K dbuf dead); hides V latency under exp ----
#pragma unroll
    for (int p = 0; p < 4; ++p) {
      int idx = p * 512 + tid;
      int feat = idx >> 3, gs = idx & 7;
      gll(vt + (size_t)feat * NN + c0 + ((gs ^ (feat & 7)) * 8),
          &KV[(p * 512 + wbase) * 8]);
    }
    // ---- exp + packed P->LDS (S^T: lane holds 4 consecutive cols/row) ----
#pragma unroll
    for (int rt = 0; rt < 2; ++rt) {
      int row = wr * 32 + rt * 16 + l15;
#pragma unroll
      for (int ct = 0; ct < 2; ++ct) {
        s16x4 pk;
#pragma unroll
        for (int r = 0; r < 4; ++r) {
          float pv = exp2f(s[ct][rt][r] * SCALE_LOG2E);
          den[rt] += pv;
          pk[r] = f2b(pv);
        }
        int cg = wc * 4 + ct * 2 + (quad >> 1);  // col granule = col>>3
        *reinterpret_cast<s16x4*>(
            &Ps[row * 128 + ((cg ^ (row & 7)) * 8 + (quad & 1) * 4)]) = pk;
      }
    }
    __syncthreads();  // drains Ps (lgkm) + V jb=0 (vm)
    // ---- PV: V subtiles of 64 cols ----
#pragma unroll
    for (int jb = 0; jb < 2; ++jb) {
      if (jb == 1) {
        __syncthreads();  // all jb=0 vb reads done before restage
#pragma unroll
        for (int p = 0; p < 4; ++p) {
          int idx = p * 512 + tid;
          int feat = idx >> 3, gs = idx & 7;
          gll(vt + (size_t)feat * NN + c0 + 64 + ((gs ^ (feat & 7)) * 8),
              &KV[(p * 512 + wbase) * 8]);
        }
        __syncthreads();
      }
#pragma unroll
      for (int ks = 0; ks < 2; ++ks) {
        int g = ks * 4 + quad;
        bf16x8 pa[2], vb[4];
#pragma unroll
        for (int rt = 0; rt < 2; ++rt) {
          int row = wr * 32 + rt * 16 + l15;
          pa[rt] = *(const bf16x8*)&Ps[row * 128 +
                                       (((jb * 8 + g) ^ (row & 7)) * 8)];
        }
#pragma unroll
        for (int ft = 0; ft < 4; ++ft)
          vb[ft] = *(const bf16x8*)&KV[(wc * 64 + ft * 16 + l15) * 64 + (g ^ rsw) * 8];
#pragma unroll
        for (int rt = 0; rt < 2; ++rt)
#pragma unroll
          for (int ft = 0; ft < 4; ++ft)
            o[rt][ft] = __builtin_amdgcn_mfma_f32_16x16x32_bf16(pa[rt], vb[ft],
                                                                o[rt][ft], 0, 0, 0);
      }
    }
    __syncthreads();  // protect Ps/KV rewrite next chunk
  }
  // ---- epilogue: write partial num ----
  float* npB = nump + (size_t)q * NN * DQK;
#pragma unroll
  for (int rt = 0; rt < 2; ++rt)
#pragma unroll
    for (int ft = 0; ft < 4; ++ft) {
      int row = r0 + wr * 32 + rt * 16 + quad * 4;
      int feat = wc * 64 + ft * 16 + l15;
#pragma unroll
      for (int r = 0; r < 4; ++r)
        npB[(size_t)(row + r) * DQK + feat] = o[rt][ft][r];
    }
  // ---- den: S^T layout -> row = rt*16+l15; reduce across quads, then wc ----
  float* dl = reinterpret_cast<float*>(KV);  // [4][TBM], KV dead at epilogue
#pragma unroll
  for (int rt = 0; rt < 2; ++rt) {
    float d = den[rt];
    d += __shfl_xor(d, 16);
    d += __shfl_xor(d, 32);
    if (lane < 16) dl[wc * TBM + wr * 32 + rt * 16 + lane] = d;
  }
  __syncthreads();
  if (tid < TBM) {
    float d = dl[0 * TBM + tid] + dl[1 * TBM + tid] + dl[2 * TBM + tid] +
              dl[3 * TBM + tid];
    denp[q * NN + r0 + tid] = d;
  }
}

// ---------------- K6: single-pass combine (R20) ------------------------------
// R19 attribution: k6 ~70-76us vs ~50us gather-traffic floor (K 134MB + V
// 134MB + nump 33MB). R20: fuse the old 2-phase (score-gather then V-gather)
// into ONE loop: 16 lanes/edge, 4 edges in flight; each lane gathers the
// MATCHING 32B K and V slices of row j together (2x outstanding loads), dot
// via shfl_xor(1,2,4,8), delta broadcast to all 16 lanes, delta*V accumulated
// in regs. Cross-group reduce via shfl_xor(16,32) only - no reduction LDS,
// no ess[] buffer, 2 fewer barriers. Same per-edge math; fp reorder only.
__global__ __launch_bounds__(64) void k6_combine(
    const int* __restrict__ eidx, const float* __restrict__ bias,
    const int* __restrict__ cntArr, const int* __restrict__ slot,
    const short* __restrict__ qk, const short* __restrict__ vb16,
    const float* __restrict__ nump, const float* __restrict__ denp,
    float* __restrict__ out, int nsplit) {
  __shared__ short qs[DQK];
  __shared__ int js[CAP];
  __shared__ float bs[CAP];
  __shared__ int keepf[CAP];
  int i = blockIdx.x;
  int lane = threadIdx.x;
  int cnt = cntArr[i];
  if (cnt > CAP) cnt = CAP;
  *reinterpret_cast<s16x4*>(&qs[lane * 4]) =
      *reinterpret_cast<const s16x4*>(qk + (size_t)i * DQK + lane * 4);
  for (int p = lane; p < cnt; p += 64) {
    int e = slot[i * CAP + p];
    js[p] = eidx[EE + e];
    bs[p] = bias[e];
  }
  __syncthreads();
  // ---- exact duplicate-(i,j) merge: first occurrence keeps summed beta ----
  {
    int myp[2];
    float mybsum[2];
    int mykeep[2];
    int nm = 0;
    for (int p = lane; p < cnt; p += 64) {
      int j = js[p];
      float bsum = bs[p];
      int keep = 1;
      for (int qq = 0; qq < cnt; ++qq) {
        if (qq == p || js[qq] != j) continue;
        if (qq < p) { keep = 0; break; }
        bsum += bs[qq];
      }
      myp[nm] = p; mybsum[nm] = bsum; mykeep[nm] = keep; ++nm;
    }
    __syncthreads();
    for (int k = 0; k < nm; ++k) { bs[myp[k]] = mybsum[k]; keepf[myp[k]] = mykeep[k]; }
    __syncthreads();
  }
  // ---- single pass: 16 lanes/edge, 4 edges in flight ----
  int sub = lane & 15;   // lane's 16-elem slice: shorts sub*16 .. sub*16+15
  int grp = lane >> 4;   // edge group 0..3
  const bf16x8* qa = reinterpret_cast<const bf16x8*>(qs + sub * 16);
  bf16x8 q0 = qa[0], q1 = qa[1];
  f32x4 acc[4] = {};     // feats sub*16 + 0..15
  float denc = 0.f;      // identical across the 16 lanes of grp
  for (int p = grp; p < cnt; p += 4) {
    if (!keepf[p]) continue;
    int j = js[p];
    const bf16x8* kb =
        reinterpret_cast<const bf16x8*>(qk + (size_t)j * DQK + sub * 16);
    const bf16x8* vb =
        reinterpret_cast<const bf16x8*>(vb16 + (size_t)j * DQK + sub * 16);
    bf16x8 k0 = kb[0], k1 = kb[1];
    bf16x8 v0 = vb[0], v1 = vb[1];
    float sp = 0.f;
#pragma unroll
    for (int u = 0; u < 8; ++u) sp += b2f(q0[u]) * b2f(k0[u]);
#pragma unroll
    for (int u = 0; u < 8; ++u) sp += b2f(q1[u]) * b2f(k1[u]);
    sp += __shfl_xor(sp, 1);
    sp += __shfl_xor(sp, 2);
    sp += __shfl_xor(sp, 4);
    sp += __shfl_xor(sp, 8);
    float delta = __expf(sp * SCALE) * expm1f(bs[p]);
    denc += delta;
#pragma unroll
    for (int u = 0; u < 4; ++u) {
      acc[0][u] += delta * b2f(v0[u]);
      acc[1][u] += delta * b2f(v0[4 + u]);
      acc[2][u] += delta * b2f(v1[u]);
      acc[3][u] += delta * b2f(v1[4 + u]);
    }
  }
  // ---- cross-group reduce (grp bits = lane bits 4,5) ----
#pragma unroll
  for (int t = 0; t < 4; ++t) {
#pragma unroll
    for (int u = 0; u < 4; ++u) {
      acc[t][u] += __shfl_xor(acc[t][u], 16);
      acc[t][u] += __shfl_xor(acc[t][u], 32);
    }
  }
  denc += __shfl_xor(denc, 16);
  denc += __shfl_xor(denc, 32);
  // ---- redistribute: lane l outputs feats l*4..l*4+3 ----
  // source slice sub' = l>>2 (lane l>>2 holds it), element block t = l&3
  int t3 = lane & 3;
  f32x4 sel = (t3 == 0) ? acc[0] : (t3 == 1) ? acc[1] : (t3 == 2) ? acc[2] : acc[3];
  int srcLane = lane >> 2;
  f32x4 a;
#pragma unroll
  for (int u = 0; u < 4; ++u) a[u] = __shfl(sel[u], srcLane);
  float den = denc;  // already full sum on every lane
  // ---- add dense partials + normalize + write ----
  for (int qq = 0; qq < nsplit; ++qq) {
    const float* np = nump + ((size_t)qq * NN + i) * DQK + lane * 4;
    a += *reinterpret_cast<const f32x4*>(np);
    den += denp[qq * NN + i];
  }
  float inv = 1.0f / den;
  a *= inv;
  // feats f = lane*4..+3; f<128 -> new_mag, else new_phase (no 128-crossing)
  float* dst = (lane < 32) ? (out + (size_t)i * DD + lane * 4)
                           : (out + (size_t)NN * DD + (size_t)i * DD + lane * 4 - 128);
  *reinterpret_cast<f32x4*>(dst) = a;
}

// ---------------- workspace layout -------------------------------------------
constexpr size_t OFF_QK = 0;                                   // 4 MiB bf16
constexpr size_t OFF_VT = (size_t)NN * DQK * 2;                // 4 MiB bf16
constexpr size_t OFF_VB16 = OFF_VT + (size_t)DQK * NN * 2;     // 4 MiB bf16
constexpr size_t OFF_BIAS = OFF_VB16 + (size_t)NN * DQK * 2;   // 1 MiB f32
constexpr size_t OFF_CNT = OFF_BIAS + (size_t)EE * 4;
constexpr size_t OFF_SLOT = OFF_CNT + (size_t)NN * 4;
constexpr size_t OFF_NUMP = (OFF_SLOT + (size_t)NN * CAP * 4 + 255) & ~(size_t)255;
constexpr size_t WS_NEED4 = OFF_NUMP + 4ull * NN * DQK * 4 + 4ull * NN * 4;
constexpr size_t WS_NEED2 = OFF_NUMP + 2ull * NN * DQK * 4 + 2ull * NN * 4;

extern "C" void kernel_launch(void* const* d_in, const int* in_sizes, int n_in,
                              void* d_out, int out_size, void* d_ws, size_t ws_size,
                              hipStream_t stream) {
  const float* mag = (const float*)d_in[0];
  const float* phase = (const float*)d_in[1];
  const int* eidx = (const int*)d_in[2];
  const float* rbf = (const float*)d_in[3];
  const float* W1 = (const float*)d_in[4];
  const float* b1 = (const float*)d_in[5];
  const float* W2 = (const float*)d_in[6];
  const float* b2 = (const float*)d_in[7];
  float* out = (float*)d_out;
  char* ws = (char*)d_ws;
  if (ws_size < WS_NEED2) return;
  int nsplit = (ws_size >= WS_NEED4) ? 4 : 2;

  short* qkb = (short*)(ws + OFF_QK);
  short* vtb = (short*)(ws + OFF_VT);
  short* vb16 = (short*)(ws + OFF_VB16);
  float* bias = (float*)(ws + OFF_BIAS);
  int* cnt = (int*)(ws + OFF_CNT);
  int* slot = (int*)(ws + OFF_SLOT);
  float* nump = (float*)(ws + OFF_NUMP);
  float* denp = (float*)(ws + OFF_NUMP + (size_t)nsplit * NN * DQK * 4);

  hipMemsetAsync(cnt, 0, (size_t)NN * 4, stream);
  k1_mega<<<5632, 256, 0, stream>>>(mag, phase, qkb, vtb, vb16, rbf, W1, b1, W2,
                                    b2, eidx, bias, cnt, slot);
  if (nsplit == 4)
    k5_flash<4><<<(NN / TBM) * 4, 512, 0, stream>>>(qkb, vtb, nump, denp);
  else
    k5_flash<2><<<(NN / TBM) * 2, 512, 0, stream>>>(qkb, vtb, nump, denp);
  k6_combine<<<NN, 64, 0, stream>>>(eidx, bias, cnt, slot, qkb, vb16, nump, denp,
                                    out, nsplit);
}